// Round 1
// baseline (3273.980 us; speedup 1.0000x reference)
//
#include <hip/hip_runtime.h>
#include <hip/hip_bf16.h>
#include <math.h>

#define TSEQ 2048
#define BATCH 2
#define CDIM 1024
#define NH 16
#define HD 64
#define DFF 4096
#define ROWS (BATCH*TSEQ)   // 4096

// ---------------- LayerNorm: one block per row, 256 threads, float4 ----------------
__global__ __launch_bounds__(256) void ln_kernel(const float* __restrict__ x,
                                                 const float* __restrict__ g,
                                                 const float* __restrict__ b,
                                                 float* __restrict__ out) {
    int row = blockIdx.x;
    int tid = threadIdx.x;                       // 256 threads * 4 floats = 1024
    const float* xr = x + (size_t)row * CDIM;
    float4 v = *(const float4*)(xr + tid * 4);
    float s  = v.x + v.y + v.z + v.w;
    float s2 = v.x*v.x + v.y*v.y + v.z*v.z + v.w*v.w;
    #pragma unroll
    for (int off = 32; off >= 1; off >>= 1) {
        s  += __shfl_down(s, off);
        s2 += __shfl_down(s2, off);
    }
    __shared__ float red[8];
    int wid = tid >> 6, lane = tid & 63;
    if (lane == 0) { red[wid] = s; red[wid + 4] = s2; }
    __syncthreads();
    float ts  = red[0] + red[1] + red[2] + red[3];
    float ts2 = red[4] + red[5] + red[6] + red[7];
    float mu  = ts * (1.0f / CDIM);
    float var = ts2 * (1.0f / CDIM) - mu * mu;
    float rstd = rsqrtf(var + 1e-5f);
    float4 gv = *(const float4*)(g + tid * 4);
    float4 bv = *(const float4*)(b + tid * 4);
    float4 o;
    o.x = (v.x - mu) * rstd * gv.x + bv.x;
    o.y = (v.y - mu) * rstd * gv.y + bv.y;
    o.z = (v.z - mu) * rstd * gv.z + bv.z;
    o.w = (v.w - mu) * rstd * gv.w + bv.w;
    *(float4*)(out + (size_t)row * CDIM + tid * 4) = o;
}

// ---------------- fp32 tiled GEMM: C[M,N] = A[M,K] @ B[K,N] + bias (+epilogue) ------
// EPI: 0 = bias only, 1 = bias + residual add, 2 = bias + exact GELU
template<int EPI>
__global__ __launch_bounds__(256) void gemm_kernel(const float* __restrict__ A,
                                                   const float* __restrict__ B,
                                                   const float* __restrict__ bias,
                                                   const float* __restrict__ res,
                                                   float* __restrict__ C,
                                                   int M, int N, int K) {
    __shared__ float As[16][64];
    __shared__ float Bs[16][64];
    int tid  = threadIdx.x;
    int bcol = blockIdx.x * 64;
    int brow = blockIdx.y * 64;
    int tx = tid & 15, ty = tid >> 4;            // 16x16 threads, 4x4 micro-tile
    float acc[4][4] = {};
    int ar = tid >> 2, ac = (tid & 3) * 4;       // A tile: 64 rows x 16 cols
    int br = tid >> 4, bc = (tid & 15) * 4;      // B tile: 16 rows x 64 cols

    for (int k0 = 0; k0 < K; k0 += 16) {
        float4 av = *(const float4*)&A[(size_t)(brow + ar) * K + k0 + ac];
        float4 bv = *(const float4*)&B[(size_t)(k0 + br) * N + bcol + bc];
        As[ac + 0][ar] = av.x;
        As[ac + 1][ar] = av.y;
        As[ac + 2][ar] = av.z;
        As[ac + 3][ar] = av.w;
        *(float4*)&Bs[br][bc] = bv;
        __syncthreads();
        #pragma unroll
        for (int kk = 0; kk < 16; ++kk) {
            float4 a4 = *(const float4*)&As[kk][ty * 4];
            float4 b4 = *(const float4*)&Bs[kk][tx * 4];
            float a[4] = {a4.x, a4.y, a4.z, a4.w};
            float bb[4] = {b4.x, b4.y, b4.z, b4.w};
            #pragma unroll
            for (int i = 0; i < 4; ++i)
                #pragma unroll
                for (int j = 0; j < 4; ++j)
                    acc[i][j] = fmaf(a[i], bb[j], acc[i][j]);
        }
        __syncthreads();
    }

    #pragma unroll
    for (int i = 0; i < 4; ++i) {
        int row = brow + ty * 4 + i;
        #pragma unroll
        for (int j = 0; j < 4; ++j) {
            int col = bcol + tx * 4 + j;
            float v = acc[i][j] + bias[col];
            if (EPI == 1) v += res[(size_t)row * N + col];
            if (EPI == 2) v = 0.5f * v * (1.0f + erff(v * 0.70710678118f));
            C[(size_t)row * N + col] = v;
        }
    }
}

// ---------------- causal flash attention, 64x64 tiles, fp32 ------------------------
// qkv layout per row (3072): [ q(0..1023) | k(1024..2047) | v(2048..3071) ],
// each 1024 = h*64 + d.  grid = (TSEQ/64, BATCH*NH), block = 256.
__global__ __launch_bounds__(256) void attn_kernel(const float* __restrict__ qkv,
                                                   float* __restrict__ out) {
    __shared__ float Qs[64][65];
    __shared__ float Ks[64][65];
    __shared__ float Vs[64][65];
    __shared__ float Ps[64][65];

    int tid = threadIdx.x;
    int qi  = blockIdx.x;                 // query tile index
    int bh  = blockIdx.y;
    int b   = bh >> 4, h = bh & 15;
    int r   = tid >> 2;                   // row within tile, 0..63
    int sub = tid & 3;                    // 4 threads per row

    const size_t base = (size_t)b * TSEQ * 3 * CDIM;
    const int    rstr = 3 * CDIM;         // 3072

    // load Q tile, pre-scaled by 1/sqrt(64)
    {
        int lr = tid >> 2;
        int lc = (tid & 3) * 16;
        const float* src = qkv + base + (size_t)(qi * 64 + lr) * rstr + h * HD + lc;
        #pragma unroll
        for (int i = 0; i < 4; ++i) {
            float4 v = *(const float4*)(src + i * 4);
            Qs[lr][lc + i*4 + 0] = v.x * 0.125f;
            Qs[lr][lc + i*4 + 1] = v.y * 0.125f;
            Qs[lr][lc + i*4 + 2] = v.z * 0.125f;
            Qs[lr][lc + i*4 + 3] = v.w * 0.125f;
        }
    }

    float m = -INFINITY, l = 0.0f;
    float o[16];
    #pragma unroll
    for (int i = 0; i < 16; ++i) o[i] = 0.0f;

    for (int j = 0; j <= qi; ++j) {
        __syncthreads();   // previous-iteration reads done before overwrite (also orders Q write)
        {
            int lr = tid >> 2;
            int lc = (tid & 3) * 16;
            const float* ksrc = qkv + base + (size_t)(j * 64 + lr) * rstr + CDIM + h * HD + lc;
            const float* vsrc = ksrc + CDIM;
            #pragma unroll
            for (int i = 0; i < 4; ++i) {
                float4 kv = *(const float4*)(ksrc + i * 4);
                Ks[lr][lc + i*4 + 0] = kv.x;
                Ks[lr][lc + i*4 + 1] = kv.y;
                Ks[lr][lc + i*4 + 2] = kv.z;
                Ks[lr][lc + i*4 + 3] = kv.w;
                float4 vv = *(const float4*)(vsrc + i * 4);
                Vs[lr][lc + i*4 + 0] = vv.x;
                Vs[lr][lc + i*4 + 1] = vv.y;
                Vs[lr][lc + i*4 + 2] = vv.z;
                Vs[lr][lc + i*4 + 3] = vv.w;
            }
        }
        __syncthreads();

        // scores: this thread computes s[c] for c = sub*16 .. sub*16+15
        float s[16];
        #pragma unroll
        for (int cc = 0; cc < 16; ++cc) s[cc] = 0.0f;
        for (int d4 = 0; d4 < 64; d4 += 4) {
            float4 q4 = *(const float4*)&Qs[r][d4];
            #pragma unroll
            for (int cc = 0; cc < 16; ++cc) {
                float4 k4 = *(const float4*)&Ks[sub * 16 + cc][d4];
                s[cc] += q4.x*k4.x + q4.y*k4.y + q4.z*k4.z + q4.w*k4.w;
            }
        }

        // causal mask on the diagonal tile
        if (j == qi) {
            int qrow  = r;
            int cbase = sub * 16;
            #pragma unroll
            for (int cc = 0; cc < 16; ++cc)
                if (cbase + cc > qrow) s[cc] = -INFINITY;
        }

        // online softmax
        float tmax = s[0];
        #pragma unroll
        for (int cc = 1; cc < 16; ++cc) tmax = fmaxf(tmax, s[cc]);
        tmax = fmaxf(tmax, __shfl_xor(tmax, 1));
        tmax = fmaxf(tmax, __shfl_xor(tmax, 2));
        float mnew  = fmaxf(m, tmax);
        float alpha = __expf(m - mnew);
        float p[16], psum = 0.0f;
        #pragma unroll
        for (int cc = 0; cc < 16; ++cc) { p[cc] = __expf(s[cc] - mnew); psum += p[cc]; }
        psum += __shfl_xor(psum, 1);
        psum += __shfl_xor(psum, 2);
        l = l * alpha + psum;
        m = mnew;
        #pragma unroll
        for (int i = 0; i < 16; ++i) o[i] *= alpha;
        #pragma unroll
        for (int cc = 0; cc < 16; ++cc) Ps[r][sub * 16 + cc] = p[cc];
        __syncthreads();

        // O accumulation: o[dd] += sum_c P[r][c] * V[c][sub*16+dd]
        for (int c = 0; c < 64; ++c) {
            float pv = Ps[r][c];
            #pragma unroll
            for (int i = 0; i < 4; ++i) {
                float4 v4 = *(const float4*)&Vs[c][sub * 16 + i * 4];
                o[i*4 + 0] = fmaf(pv, v4.x, o[i*4 + 0]);
                o[i*4 + 1] = fmaf(pv, v4.y, o[i*4 + 1]);
                o[i*4 + 2] = fmaf(pv, v4.z, o[i*4 + 2]);
                o[i*4 + 3] = fmaf(pv, v4.w, o[i*4 + 3]);
            }
        }
    }

    float inv = 1.0f / l;
    float* dst = out + (size_t)(b * TSEQ + qi * 64 + r) * CDIM + h * HD + sub * 16;
    #pragma unroll
    for (int i = 0; i < 4; ++i) {
        float4 ov;
        ov.x = o[i*4 + 0] * inv;
        ov.y = o[i*4 + 1] * inv;
        ov.z = o[i*4 + 2] * inv;
        ov.w = o[i*4 + 3] * inv;
        *(float4*)(dst + i * 4) = ov;
    }
}

extern "C" void kernel_launch(void* const* d_in, const int* in_sizes, int n_in,
                              void* d_out, int out_size, void* d_ws, size_t ws_size,
                              hipStream_t stream) {
    const float* x     = (const float*)d_in[0];
    const float* ln1_g = (const float*)d_in[1];
    const float* ln1_b = (const float*)d_in[2];
    const float* w_qkv = (const float*)d_in[3];
    const float* b_qkv = (const float*)d_in[4];
    const float* w_out = (const float*)d_in[5];
    const float* b_out = (const float*)d_in[6];
    const float* ln2_g = (const float*)d_in[7];
    const float* ln2_b = (const float*)d_in[8];
    const float* w_ff1 = (const float*)d_in[9];
    const float* b_ff1 = (const float*)d_in[10];
    const float* w_ff2 = (const float*)d_in[11];
    const float* b_ff2 = (const float*)d_in[12];
    float* out = (float*)d_out;

    float* ws   = (float*)d_ws;
    float* h    = ws;                                  // 4096*1024   (reused for LN2 out)
    float* qkv  = h    + (size_t)ROWS * CDIM;          // 4096*3072
    float* attn = qkv  + (size_t)ROWS * 3 * CDIM;      // 4096*1024
    float* x1   = attn + (size_t)ROWS * CDIM;          // 4096*1024
    float* ff1  = qkv;                                 // 4096*4096 overlays dead qkv+attn

    // 1. LN1
    ln_kernel<<<ROWS, 256, 0, stream>>>(x, ln1_g, ln1_b, h);
    // 2. qkv = h @ w_qkv + b_qkv
    gemm_kernel<0><<<dim3(3 * CDIM / 64, ROWS / 64), 256, 0, stream>>>(
        h, w_qkv, b_qkv, nullptr, qkv, ROWS, 3 * CDIM, CDIM);
    // 3. causal attention
    attn_kernel<<<dim3(TSEQ / 64, BATCH * NH), 256, 0, stream>>>(qkv, attn);
    // 4. x1 = x + attn @ w_out + b_out
    gemm_kernel<1><<<dim3(CDIM / 64, ROWS / 64), 256, 0, stream>>>(
        attn, w_out, b_out, x, x1, ROWS, CDIM, CDIM);
    // 5. LN2 (into h)
    ln_kernel<<<ROWS, 256, 0, stream>>>(x1, ln2_g, ln2_b, h);
    // 6. ff1 = gelu(h @ w_ff1 + b_ff1)
    gemm_kernel<2><<<dim3(DFF / 64, ROWS / 64), 256, 0, stream>>>(
        h, w_ff1, b_ff1, nullptr, ff1, ROWS, DFF, CDIM);
    // 7. out = x1 + ff1 @ w_ff2 + b_ff2
    gemm_kernel<1><<<dim3(CDIM / 64, ROWS / 64), 256, 0, stream>>>(
        ff1, w_ff2, b_ff2, x1, out, ROWS, CDIM, DFF);
}

// Round 2
// 397.226 us; speedup vs baseline: 8.2421x; 8.2421x over previous
//
#include <hip/hip_runtime.h>
#include <hip/hip_bf16.h>
#include <math.h>

#define TSEQ 2048
#define BATCH 2
#define CDIM 1024
#define NH 16
#define HD 64
#define DFF 4096
#define ROWS (BATCH*TSEQ)   // 4096

typedef __attribute__((ext_vector_type(4))) float f32x4;
typedef __attribute__((ext_vector_type(8))) short bf16x8;   // 8 bf16 in 4 VGPRs
typedef __attribute__((ext_vector_type(4))) unsigned short u16x4;

__device__ __forceinline__ void gload_lds16(const void* g, void* l) {
    void* gv = const_cast<void*>(g);
    __builtin_amdgcn_global_load_lds((__attribute__((address_space(1))) void*)gv,
                                     (__attribute__((address_space(3))) void*)l, 16, 0, 0);
}

__device__ __forceinline__ unsigned short f2bf(float f) {
    unsigned int u = __float_as_uint(f);
    return (unsigned short)((u + 0x7FFFu + ((u >> 16) & 1u)) >> 16);
}

// ------------------------------- LayerNorm -> bf16 --------------------------------
__global__ __launch_bounds__(256) void ln_kernel(const float* __restrict__ x,
                                                 const float* __restrict__ g,
                                                 const float* __restrict__ b,
                                                 unsigned short* __restrict__ out) {
    int row = blockIdx.x;
    int tid = threadIdx.x;
    const float* xr = x + (size_t)row * CDIM;
    float4 v = *(const float4*)(xr + tid * 4);
    float s  = v.x + v.y + v.z + v.w;
    float s2 = v.x*v.x + v.y*v.y + v.z*v.z + v.w*v.w;
    #pragma unroll
    for (int off = 32; off >= 1; off >>= 1) {
        s  += __shfl_down(s, off);
        s2 += __shfl_down(s2, off);
    }
    __shared__ float red[8];
    int wid = tid >> 6, lane = tid & 63;
    if (lane == 0) { red[wid] = s; red[wid + 4] = s2; }
    __syncthreads();
    float ts  = red[0] + red[1] + red[2] + red[3];
    float ts2 = red[4] + red[5] + red[6] + red[7];
    float mu  = ts * (1.0f / CDIM);
    float var = ts2 * (1.0f / CDIM) - mu * mu;
    float rstd = rsqrtf(var + 1e-5f);
    float4 gv = *(const float4*)(g + tid * 4);
    float4 bv = *(const float4*)(b + tid * 4);
    unsigned short o4[4];
    o4[0] = f2bf((v.x - mu) * rstd * gv.x + bv.x);
    o4[1] = f2bf((v.y - mu) * rstd * gv.y + bv.y);
    o4[2] = f2bf((v.z - mu) * rstd * gv.z + bv.z);
    o4[3] = f2bf((v.w - mu) * rstd * gv.w + bv.w);
    *(u16x4*)(out + (size_t)row * CDIM + tid * 4) = *(u16x4*)o4;
}

// --------------------- transpose + cast: W[K][N] f32 -> Wt[N][K] bf16 ---------------
__global__ __launch_bounds__(256) void transpose_cast_kernel(const float* __restrict__ W,
                                                             unsigned short* __restrict__ Wt,
                                                             int K, int N) {
    __shared__ float T[64][65];
    int tid = threadIdx.x;
    int n0 = blockIdx.x * 64, k0 = blockIdx.y * 64;
    int kr = tid >> 4;
    int nc = (tid & 15) * 4;
    #pragma unroll
    for (int i = 0; i < 4; ++i) {
        float4 v = *(const float4*)&W[(size_t)(k0 + kr + i*16) * N + (n0 + nc)];
        T[kr + i*16][nc + 0] = v.x;
        T[kr + i*16][nc + 1] = v.y;
        T[kr + i*16][nc + 2] = v.z;
        T[kr + i*16][nc + 3] = v.w;
    }
    __syncthreads();
    int n  = tid >> 2;
    int kb = (tid & 3) * 16;
    unsigned short tmp[16];
    #pragma unroll
    for (int i = 0; i < 16; ++i) tmp[i] = f2bf(T[kb + i][n]);
    unsigned short* dst = Wt + (size_t)(n0 + n) * K + (k0 + kb);
    *(int4*)dst       = *(int4*)&tmp[0];
    *(int4*)(dst + 8) = *(int4*)&tmp[8];
}

// ---------------- MFMA GEMM (TN): C[M,N] = A[M,K](bf16) @ Bt[N,K](bf16)^T ----------
// EPI: 0 = bias -> bf16 out; 1 = bias + f32 residual -> f32 out; 2 = bias+GELU -> bf16 out
template<int EPI>
__global__ __launch_bounds__(256) void gemm_kernel(const unsigned short* __restrict__ A,
                                                   const unsigned short* __restrict__ Bt,
                                                   const float* __restrict__ bias,
                                                   const float* __restrict__ res,
                                                   void* __restrict__ Cout,
                                                   int M, int N, int K) {
    __shared__ __align__(16) unsigned short As[128 * 32];
    __shared__ __align__(16) unsigned short Bs[128 * 32];
    const int tid = threadIdx.x;
    const int l   = tid & 63;
    const int w   = tid >> 6;
    const int wr  = (w >> 1) * 64;          // wave quadrant
    const int wc  = (w & 1) * 64;
    const long brow = (long)blockIdx.y * 128;
    const long bcol = (long)blockIdx.x * 128;

    // staging: thread covers 16B chunk tid (rows 0..63) and 256+tid (rows 64..127)
    const unsigned short* gA0 = A  + (size_t)(brow + (tid >> 2)) * K + (tid & 3) * 8;
    const unsigned short* gA1 = gA0 + (size_t)64 * K;
    const unsigned short* gB0 = Bt + (size_t)(bcol + (tid >> 2)) * K + (tid & 3) * 8;
    const unsigned short* gB1 = gB0 + (size_t)64 * K;
    unsigned short* lA0 = As + tid * 8;
    unsigned short* lA1 = As + 2048 + tid * 8;
    unsigned short* lB0 = Bs + tid * 8;
    unsigned short* lB1 = Bs + 2048 + tid * 8;

    f32x4 acc[4][4];
    #pragma unroll
    for (int m = 0; m < 4; ++m)
        #pragma unroll
        for (int n = 0; n < 4; ++n) acc[m][n] = (f32x4){0.f, 0.f, 0.f, 0.f};

    const int aoff = (wr + (l & 15)) * 32 + (l >> 4) * 8;   // + m*512
    const int boff = (wc + (l & 15)) * 32 + (l >> 4) * 8;   // + n*512

    for (int k0 = 0; k0 < K; k0 += 32) {
        gload_lds16(gA0 + k0, lA0);
        gload_lds16(gA1 + k0, lA1);
        gload_lds16(gB0 + k0, lB0);
        gload_lds16(gB1 + k0, lB1);
        __syncthreads();                    // vmcnt drained by compiler before barrier
        bf16x8 af[4], bf[4];
        #pragma unroll
        for (int m = 0; m < 4; ++m) af[m] = *(const bf16x8*)&As[aoff + m * 512];
        #pragma unroll
        for (int n = 0; n < 4; ++n) bf[n] = *(const bf16x8*)&Bs[boff + n * 512];
        #pragma unroll
        for (int m = 0; m < 4; ++m)
            #pragma unroll
            for (int n = 0; n < 4; ++n)
                acc[m][n] = __builtin_amdgcn_mfma_f32_16x16x32_bf16(af[m], bf[n], acc[m][n], 0, 0, 0);
        __syncthreads();                    // reads done before next stage overwrites
    }

    // epilogue: C row = (l>>4)*4 + r, col = l&15 within each 16x16 frag (HW-verified)
    #pragma unroll
    for (int m = 0; m < 4; ++m) {
        const int rown = wr + m * 16 + (l >> 4) * 4;
        #pragma unroll
        for (int n = 0; n < 4; ++n) {
            const long col = bcol + wc + n * 16 + (l & 15);
            const float bb = bias[col];
            #pragma unroll
            for (int r = 0; r < 4; ++r) {
                const long row = brow + rown + r;
                float v = acc[m][n][r] + bb;
                if (EPI == 1) {
                    v += res[row * N + col];
                    ((float*)Cout)[row * N + col] = v;
                } else if (EPI == 2) {
                    v = 0.5f * v * (1.0f + erff(v * 0.70710678118f));
                    ((unsigned short*)Cout)[row * N + col] = f2bf(v);
                } else {
                    ((unsigned short*)Cout)[row * N + col] = f2bf(v);
                }
            }
        }
    }
}

// ------------------------- MFMA causal flash attention ----------------------------
// qkv: bf16 [4096][3072] (q|k|v each 1024 = h*64+d). grid (TSEQ/64, BATCH*NH), 256 thr.
__global__ __launch_bounds__(256) void attn_kernel(const unsigned short* __restrict__ qkv,
                                                   unsigned short* __restrict__ out) {
    __shared__ __align__(16) unsigned short Ks[64 * 64];   // [s][d], chunk-XOR swizzled
    __shared__ __align__(16) unsigned short Ps[64 * 64];   // [q][s], chunk-XOR swizzled
    __shared__ __align__(16) unsigned short Vt[64 * 72];   // [d][s], padded

    const int tid = threadIdx.x;
    const int l   = tid & 63;
    const int w   = tid >> 6;
    const int qi  = gridDim.x - 1 - blockIdx.x;   // longest blocks launch first
    const int bh  = blockIdx.y;
    const int b   = bh >> 4, h = bh & 15;
    const size_t rowbase = (size_t)b * TSEQ;

    // hoisted Q fragments (A operand, rows l&15 of this wave's 16 q-rows)
    bf16x8 aq0, aq1;
    {
        const int qrow = qi * 64 + w * 16 + (l & 15);
        const unsigned short* qp = qkv + (rowbase + qrow) * 3072 + h * 64 + (l >> 4) * 8;
        aq0 = *(const bf16x8*)qp;
        aq1 = *(const bf16x8*)(qp + 32);
    }

    // K staging map: thread covers LDS chunk tid (and 256+tid); pos c' holds global chunk c'^(<row&7)
    const int krow = tid >> 3;                  // 0..31
    const int kchk = (tid & 7) ^ (krow & 7);    // global chunk to fetch
    // V staging: thread covers s = tid&63, d-group (tid>>6)*16
    const int vs  = tid & 63;
    const int vd0 = (tid >> 6) * 16;

    float mrow[4], lrow[4];
    #pragma unroll
    for (int r = 0; r < 4; ++r) { mrow[r] = -INFINITY; lrow[r] = 0.f; }
    f32x4 o[4];
    #pragma unroll
    for (int d = 0; d < 4; ++d) o[d] = (f32x4){0.f, 0.f, 0.f, 0.f};

    for (int j = 0; j <= qi; ++j) {
        __syncthreads();   // previous tile's reads complete before restaging
        {   // K tile via global_load_lds, inverse-swizzled global source
            const unsigned short* g0 = qkv + (rowbase + j * 64 + krow) * 3072 + 1024 + h * 64 + kchk * 8;
            gload_lds16(g0, Ks + tid * 8);
            const unsigned short* g1 = g0 + (size_t)32 * 3072;
            gload_lds16(g1, Ks + 2048 + tid * 8);
        }
        {   // V tile, transposed into Vt[d][s] via registers
            const unsigned short* vg = qkv + (rowbase + j * 64 + vs) * 3072 + 2048 + h * 64 + vd0;
            bf16x8 v0 = *(const bf16x8*)vg;
            bf16x8 v1 = *(const bf16x8*)(vg + 8);
            #pragma unroll
            for (int i = 0; i < 8; ++i) {
                Vt[(vd0 + i) * 72 + vs]     = (unsigned short)v0[i];
                Vt[(vd0 + 8 + i) * 72 + vs] = (unsigned short)v1[i];
            }
        }
        __syncthreads();

        // S = Q K^T : 4 col-blocks x (K=64 as 2 mfma)
        f32x4 sf[4];
        #pragma unroll
        for (int sb = 0; sb < 4; ++sb) {
            sf[sb] = (f32x4){0.f, 0.f, 0.f, 0.f};
            const int srow = sb * 16 + (l & 15);
            const int sw   = srow & 7;
            bf16x8 b0 = *(const bf16x8*)&Ks[srow * 64 + (((l >> 4)    ) ^ sw) * 8];
            bf16x8 b1 = *(const bf16x8*)&Ks[srow * 64 + (((l >> 4) + 4) ^ sw) * 8];
            sf[sb] = __builtin_amdgcn_mfma_f32_16x16x32_bf16(aq0, b0, sf[sb], 0, 0, 0);
            sf[sb] = __builtin_amdgcn_mfma_f32_16x16x32_bf16(aq1, b1, sf[sb], 0, 0, 0);
        }

        // scale + causal mask (diagonal tile only; local compare suffices)
        #pragma unroll
        for (int sb = 0; sb < 4; ++sb)
            #pragma unroll
            for (int r = 0; r < 4; ++r) sf[sb][r] *= 0.125f;
        if (j == qi) {
            const int qrl = w * 16 + (l >> 4) * 4;
            #pragma unroll
            for (int sb = 0; sb < 4; ++sb) {
                const int scol = sb * 16 + (l & 15);
                #pragma unroll
                for (int r = 0; r < 4; ++r)
                    if (scol > qrl + r) sf[sb][r] = -INFINITY;
            }
        }

        // online softmax: row r lives in lanes sharing (l>>4); reduce across low 4 lane bits
        float mnew[4], alpha[4], psum[4];
        #pragma unroll
        for (int r = 0; r < 4; ++r) {
            float mx = fmaxf(fmaxf(sf[0][r], sf[1][r]), fmaxf(sf[2][r], sf[3][r]));
            mx = fmaxf(mx, __shfl_xor(mx, 1));
            mx = fmaxf(mx, __shfl_xor(mx, 2));
            mx = fmaxf(mx, __shfl_xor(mx, 4));
            mx = fmaxf(mx, __shfl_xor(mx, 8));
            float mn = fmaxf(mrow[r], mx);
            mnew[r]  = mn;
            alpha[r] = __expf(mrow[r] - mn);
            mrow[r]  = mn;
        }
        #pragma unroll
        for (int r = 0; r < 4; ++r) psum[r] = 0.f;
        #pragma unroll
        for (int sb = 0; sb < 4; ++sb) {
            const int scol = sb * 16 + (l & 15);
            #pragma unroll
            for (int r = 0; r < 4; ++r) {
                float p = __expf(sf[sb][r] - mnew[r]);   // exp(-inf)=0 handles mask
                psum[r] += p;
                const int prow = w * 16 + (l >> 4) * 4 + r;
                Ps[prow * 64 + (((scol >> 3) ^ (prow & 7)) * 8) + (scol & 7)] = f2bf(p);
            }
        }
        #pragma unroll
        for (int r = 0; r < 4; ++r) {
            float ps = psum[r];
            ps += __shfl_xor(ps, 1);
            ps += __shfl_xor(ps, 2);
            ps += __shfl_xor(ps, 4);
            ps += __shfl_xor(ps, 8);
            lrow[r] = lrow[r] * alpha[r] + ps;
            #pragma unroll
            for (int d = 0; d < 4; ++d) o[d][r] *= alpha[r];
        }

        // O += P V   (P rows are wave-private: no barrier needed, lgkmcnt orders writes)
        #pragma unroll
        for (int kb = 0; kb < 2; ++kb) {
            const int prow = w * 16 + (l & 15);
            bf16x8 pa = *(const bf16x8*)&Ps[prow * 64 + ((kb * 4 + (l >> 4)) ^ (prow & 7)) * 8];
            #pragma unroll
            for (int d = 0; d < 4; ++d) {
                bf16x8 bv = *(const bf16x8*)&Vt[(d * 16 + (l & 15)) * 72 + kb * 32 + (l >> 4) * 8];
                o[d] = __builtin_amdgcn_mfma_f32_16x16x32_bf16(pa, bv, o[d], 0, 0, 0);
            }
        }
    }

    // epilogue: O / l -> bf16
    const int orow = qi * 64 + w * 16 + (l >> 4) * 4;
    #pragma unroll
    for (int r = 0; r < 4; ++r) {
        const float inv = 1.0f / lrow[r];
        const size_t rb = (rowbase + orow + r) * (size_t)CDIM + h * 64 + (l & 15);
        #pragma unroll
        for (int d = 0; d < 4; ++d)
            out[rb + d * 16] = f2bf(o[d][r] * inv);
    }
}

extern "C" void kernel_launch(void* const* d_in, const int* in_sizes, int n_in,
                              void* d_out, int out_size, void* d_ws, size_t ws_size,
                              hipStream_t stream) {
    const float* x     = (const float*)d_in[0];
    const float* ln1_g = (const float*)d_in[1];
    const float* ln1_b = (const float*)d_in[2];
    const float* w_qkv = (const float*)d_in[3];
    const float* b_qkv = (const float*)d_in[4];
    const float* w_out = (const float*)d_in[5];
    const float* b_out = (const float*)d_in[6];
    const float* ln2_g = (const float*)d_in[7];
    const float* ln2_b = (const float*)d_in[8];
    const float* w_ff1 = (const float*)d_in[9];
    const float* b_ff1 = (const float*)d_in[10];
    const float* w_ff2 = (const float*)d_in[11];
    const float* b_ff2 = (const float*)d_in[12];
    float* out = (float*)d_out;

    char* wsb = (char*)d_ws;
    unsigned short* h_bf    = (unsigned short*)(wsb);                          // 8 MB
    unsigned short* qkv_bf  = (unsigned short*)(wsb + 8ll  * 1024 * 1024);     // 24 MB
    unsigned short* attn_bf = (unsigned short*)(wsb + 32ll * 1024 * 1024);     // 8 MB
    float*          x1      = (float*)         (wsb + 40ll * 1024 * 1024);     // 16 MB
    unsigned short* wqkvT   = (unsigned short*)(wsb + 56ll * 1024 * 1024);     // 6 MB
    unsigned short* woutT   = (unsigned short*)(wsb + 62ll * 1024 * 1024);     // 2 MB
    unsigned short* wff1T   = (unsigned short*)(wsb + 64ll * 1024 * 1024);     // 8 MB
    unsigned short* wff2T   = (unsigned short*)(wsb + 72ll * 1024 * 1024);     // 8 MB
    unsigned short* ff1_bf  = (unsigned short*)(wsb + 8ll  * 1024 * 1024);     // 32 MB, overlays dead qkv+attn

    // weight transposes (W[K][N] -> Wt[N][K] bf16)
    transpose_cast_kernel<<<dim3(48, 16), 256, 0, stream>>>(w_qkv, wqkvT, 1024, 3072);
    transpose_cast_kernel<<<dim3(16, 16), 256, 0, stream>>>(w_out, woutT, 1024, 1024);
    transpose_cast_kernel<<<dim3(64, 16), 256, 0, stream>>>(w_ff1, wff1T, 1024, 4096);
    transpose_cast_kernel<<<dim3(16, 64), 256, 0, stream>>>(w_ff2, wff2T, 4096, 1024);

    // 1. LN1 -> bf16
    ln_kernel<<<ROWS, 256, 0, stream>>>(x, ln1_g, ln1_b, h_bf);
    // 2. qkv = h @ w_qkv + b  -> bf16
    gemm_kernel<0><<<dim3(24, 32), 256, 0, stream>>>(h_bf, wqkvT, b_qkv, nullptr, qkv_bf, ROWS, 3072, 1024);
    // 3. causal flash attention -> bf16
    attn_kernel<<<dim3(32, 32), 256, 0, stream>>>(qkv_bf, attn_bf);
    // 4. x1 = x + attn @ w_out + b  -> f32
    gemm_kernel<1><<<dim3(8, 32), 256, 0, stream>>>(attn_bf, woutT, b_out, x, x1, ROWS, 1024, 1024);
    // 5. LN2 -> bf16
    ln_kernel<<<ROWS, 256, 0, stream>>>(x1, ln2_g, ln2_b, h_bf);
    // 6. ff1 = gelu(h @ w_ff1 + b)  -> bf16
    gemm_kernel<2><<<dim3(32, 32), 256, 0, stream>>>(h_bf, wff1T, b_ff1, nullptr, ff1_bf, ROWS, 4096, 1024);
    // 7. out = x1 + ff1 @ w_ff2 + b  -> f32
    gemm_kernel<1><<<dim3(8, 32), 256, 0, stream>>>(ff1_bf, wff2T, b_ff2, x1, (float*)out, ROWS, 1024, 4096);
}